// Round 4
// baseline (12.555 us; speedup 1.0000x reference)
//
#include <hip/hip_runtime.h>
#include <hip/hip_bf16.h>

// Problem constants (B=4, D=128, N=512, fp32)
#define PB 4
#define PD 128
#define PN 512

__device__ __forceinline__ float f4get(const float4& v, int k) {
  const float* p = (const float*)&v;
  return p[k];
}

// One block = 2 full output rows (all N=512 columns) for one batch.
// grid = B * D/2 = 256 blocks, 512 threads (8 waves -> 2 waves/SIMD).
// d-axis split over 4 groups of 128 threads; thread t in group g owns
// columns [4t, 4t+4) and d-range [32g, 32g+32). float4 x loads.
// Partial (A, C) summed across groups via conflict-free b128 LDS reduce;
// row max of A is then block-local; out = relu(rowmax + C + bias - A).
__global__ __launch_bounds__(512) void gcn_one(
    const float* __restrict__ x, const float* __restrict__ W1,
    const float* __restrict__ W2, const float* __restrict__ bias,
    float* __restrict__ out) {
  const int bid = blockIdx.x;
  const int b = bid >> 6;              // batch 0..3
  const int r0 = (bid & 63) << 1;      // first of this block's 2 rows
  const int tid = threadIdx.x;
  const int g = tid >> 7;              // d-group 0..3
  const int t = tid & 127;             // column-owner within group

  __shared__ float4 ws[2][2][32];      // [mat][row][d-chunk]  : 2 KB
  __shared__ float4 red[3][4][128];    // [g-1][acc][t]        : 24 KB
  __shared__ float rmax[2][2];         // [row][half]

  // Stage 4 W-rows (W1,W2 x rows r0,r0+1), one float4 per thread (tid<128).
  if (tid < 128) {
    const int mat = tid >> 6;
    const int r = (tid >> 5) & 1;
    const int c = tid & 31;
    const float* Wm = mat ? W2 : W1;
    ws[mat][r][c] = *(const float4*)(Wm + (size_t)(r0 + r) * PD + (c << 2));
  }
  __syncthreads();

  // This thread's x base: batch b, d = 32g, col = 4t.
  const float* xp = x + (size_t)b * PD * PN + (size_t)(g << 5) * PN + (t << 2);

  float4 a0 = {0.f, 0.f, 0.f, 0.f}, a1 = a0, c0 = a0, c1 = a0;

#pragma unroll
  for (int dc = 0; dc < 8; ++dc) {     // 8 chunks x 4 d = 32 d per group
    const float4 w10 = ws[0][0][(g << 3) + dc];   // broadcast b128 reads
    const float4 w11 = ws[0][1][(g << 3) + dc];
    const float4 w20 = ws[1][0][(g << 3) + dc];
    const float4 w21 = ws[1][1][(g << 3) + dc];
    float4 xv[4];
#pragma unroll
    for (int k = 0; k < 4; ++k)
      xv[k] = *(const float4*)(xp + (size_t)((dc << 2) + k) * PN);
#pragma unroll
    for (int k = 0; k < 4; ++k) {
      const float u10 = f4get(w10, k), u11 = f4get(w11, k);
      const float u20 = f4get(w20, k), u21 = f4get(w21, k);
      a0.x = fmaf(u10, xv[k].x, a0.x); a0.y = fmaf(u10, xv[k].y, a0.y);
      a0.z = fmaf(u10, xv[k].z, a0.z); a0.w = fmaf(u10, xv[k].w, a0.w);
      a1.x = fmaf(u11, xv[k].x, a1.x); a1.y = fmaf(u11, xv[k].y, a1.y);
      a1.z = fmaf(u11, xv[k].z, a1.z); a1.w = fmaf(u11, xv[k].w, a1.w);
      c0.x = fmaf(u20, xv[k].x, c0.x); c0.y = fmaf(u20, xv[k].y, c0.y);
      c0.z = fmaf(u20, xv[k].z, c0.z); c0.w = fmaf(u20, xv[k].w, c0.w);
      c1.x = fmaf(u21, xv[k].x, c1.x); c1.y = fmaf(u21, xv[k].y, c1.y);
      c1.z = fmaf(u21, xv[k].z, c1.z); c1.w = fmaf(u21, xv[k].w, c1.w);
    }
  }

  // Cross-group reduction: groups 1..3 write partials, group 0 accumulates.
  if (g > 0) {
    red[g - 1][0][t] = a0;
    red[g - 1][1][t] = a1;
    red[g - 1][2][t] = c0;
    red[g - 1][3][t] = c1;
  }
  __syncthreads();

  if (g == 0) {
#pragma unroll
    for (int gg = 0; gg < 3; ++gg) {
      const float4 ra0 = red[gg][0][t], ra1 = red[gg][1][t];
      const float4 rc0 = red[gg][2][t], rc1 = red[gg][3][t];
      a0.x += ra0.x; a0.y += ra0.y; a0.z += ra0.z; a0.w += ra0.w;
      a1.x += ra1.x; a1.y += ra1.y; a1.z += ra1.z; a1.w += ra1.w;
      c0.x += rc0.x; c0.y += rc0.y; c0.z += rc0.z; c0.w += rc0.w;
      c1.x += rc1.x; c1.y += rc1.y; c1.z += rc1.z; c1.w += rc1.w;
    }
    // Row max of A over this thread's 4 cols, then across the 64-lane wave.
    float m0 = fmaxf(fmaxf(a0.x, a0.y), fmaxf(a0.z, a0.w));
    float m1 = fmaxf(fmaxf(a1.x, a1.y), fmaxf(a1.z, a1.w));
#pragma unroll
    for (int off = 32; off > 0; off >>= 1) {
      m0 = fmaxf(m0, __shfl_xor(m0, off));
      m1 = fmaxf(m1, __shfl_xor(m1, off));
    }
    if ((t & 63) == 0) {
      rmax[0][t >> 6] = m0;
      rmax[1][t >> 6] = m1;
    }
  }
  __syncthreads();

  if (g == 0) {
    const float M0 = fmaxf(rmax[0][0], rmax[0][1]);
    const float M1 = fmaxf(rmax[1][0], rmax[1][1]);
    const float b0 = bias[r0], b1 = bias[r0 + 1];

    float4 o0, o1;
    o0.x = fmaxf(M0 + c0.x + b0 - a0.x, 0.f);
    o0.y = fmaxf(M0 + c0.y + b0 - a0.y, 0.f);
    o0.z = fmaxf(M0 + c0.z + b0 - a0.z, 0.f);
    o0.w = fmaxf(M0 + c0.w + b0 - a0.w, 0.f);
    o1.x = fmaxf(M1 + c1.x + b1 - a1.x, 0.f);
    o1.y = fmaxf(M1 + c1.y + b1 - a1.y, 0.f);
    o1.z = fmaxf(M1 + c1.z + b1 - a1.z, 0.f);
    o1.w = fmaxf(M1 + c1.w + b1 - a1.w, 0.f);

    float* op = out + (size_t)(b * PD + r0) * PN + (t << 2);
    *(float4*)op = o0;
    *(float4*)(op + PN) = o1;
  }
}

extern "C" void kernel_launch(void* const* d_in, const int* in_sizes, int n_in,
                              void* d_out, int out_size, void* d_ws, size_t ws_size,
                              hipStream_t stream) {
  const float* x = (const float*)d_in[0];
  const float* W1 = (const float*)d_in[1];
  const float* W2 = (const float*)d_in[2];
  const float* bias = (const float*)d_in[3];
  float* out = (float*)d_out;

  gcn_one<<<dim3(PB * PD / 2), dim3(512), 0, stream>>>(x, W1, W2, bias, out);
}

// Round 5
// 10.908 us; speedup vs baseline: 1.1510x; 1.1510x over previous
//
#include <hip/hip_runtime.h>
#include <hip/hip_bf16.h>

// Problem constants (B=4, D=128, N=512, fp32)
#define PB 4
#define PD 128
#define PN 512

__device__ __forceinline__ float f4get(const float4& v, int k) {
  const float* p = (const float*)&v;
  return p[k];
}

// One block = 2 full output rows (all N=512 cols) for one batch.
// grid = B*D/2 = 256 blocks (1/CU), 512 threads (8 waves -> 2/SIMD).
// Thread layout: t = tid&127 owns 4 contiguous cols (float4 loads);
// r = (tid>>7)&1 owns one of the block's 2 rows; dh = tid>>8 owns a
// 64-d half. Each thread: 1 row x 2 mats x 4 cols x 64 d = 256 FMA-instr.
// x duplication exactly 2x (row pair) -> L1-merged; L2 bytes/block = 256KB.
// Tail: 8KB LDS pair-combine (d-halves), wave shuffle row-max, half-active
// float4 epilogue. No second kernel, no grid sync.
__global__ __launch_bounds__(512) void gcn_one(
    const float* __restrict__ x, const float* __restrict__ W1,
    const float* __restrict__ W2, const float* __restrict__ bias,
    float* __restrict__ out) {
  const int bid = blockIdx.x;
  const int b = bid >> 6;               // batch 0..3
  const int r0 = (bid & 63) << 1;       // first of the block's 2 rows
  const int tid = threadIdx.x;
  const int t = tid & 127;              // col-owner: cols [4t, 4t+4)
  const int r = (tid >> 7) & 1;         // row within pair
  const int dh = tid >> 8;              // d-half 0..1

  __shared__ float4 ws[2][2][32];       // [mat][row][d-chunk] : 2 KB
  __shared__ float4 red[2][128][2];     // [row][t][a|c]       : 8 KB
  __shared__ float rmax[2][2];          // [row][wave-half]

  // Stage 4 W-rows (W1,W2 x rows r0,r0+1), one float4 per thread (tid<128).
  if (tid < 128) {
    const int mat = tid >> 6;
    const int rr = (tid >> 5) & 1;
    const int c = tid & 31;
    const float* Wm = mat ? W2 : W1;
    ws[mat][rr][c] = *(const float4*)(Wm + (size_t)(r0 + rr) * PD + (c << 2));
  }
  __syncthreads();

  // x base: batch b, d-range [64*dh, 64*dh+64), cols [4t, 4t+4).
  const float* xp = x + (size_t)b * PD * PN + (size_t)(dh << 6) * PN + (t << 2);

  float4 a = {0.f, 0.f, 0.f, 0.f};      // W1 row dot-products (4 cols)
  float4 c = {0.f, 0.f, 0.f, 0.f};      // W2 row dot-products

#pragma unroll 4
  for (int dc = 0; dc < 16; ++dc) {     // 16 chunks x 4 d = 64 d per thread
    const int chunk = (dh << 4) + dc;
    const float4 w1v = ws[0][r][chunk]; // broadcast b128 reads, conflict-free
    const float4 w2v = ws[1][r][chunk];
    float4 xv[4];
#pragma unroll
    for (int k = 0; k < 4; ++k)
      xv[k] = *(const float4*)(xp + (size_t)((dc << 2) + k) * PN);
#pragma unroll
    for (int k = 0; k < 4; ++k) {
      const float u1 = f4get(w1v, k), u2 = f4get(w2v, k);
      a.x = fmaf(u1, xv[k].x, a.x); a.y = fmaf(u1, xv[k].y, a.y);
      a.z = fmaf(u1, xv[k].z, a.z); a.w = fmaf(u1, xv[k].w, a.w);
      c.x = fmaf(u2, xv[k].x, c.x); c.y = fmaf(u2, xv[k].y, c.y);
      c.z = fmaf(u2, xv[k].z, c.z); c.w = fmaf(u2, xv[k].w, c.w);
    }
  }

  // d-half 1 publishes partials; d-half 0 combines.
  if (dh == 1) {
    red[r][t][0] = a;
    red[r][t][1] = c;
  }
  __syncthreads();

  if (dh == 0) {
    const float4 ra = red[r][t][0], rc = red[r][t][1];
    a.x += ra.x; a.y += ra.y; a.z += ra.z; a.w += ra.w;
    c.x += rc.x; c.y += rc.y; c.z += rc.z; c.w += rc.w;

    // Row max of A: 4 local cols -> 64-lane wave -> 2 waves per row via LDS.
    float m = fmaxf(fmaxf(a.x, a.y), fmaxf(a.z, a.w));
#pragma unroll
    for (int off = 32; off > 0; off >>= 1)
      m = fmaxf(m, __shfl_xor(m, off));
    if ((t & 63) == 0) rmax[r][t >> 6] = m;
  }
  __syncthreads();

  if (dh == 0) {
    const float M = fmaxf(rmax[r][0], rmax[r][1]);
    const float bv = bias[r0 + r];
    float4 o;
    o.x = fmaxf(M + c.x + bv - a.x, 0.f);
    o.y = fmaxf(M + c.y + bv - a.y, 0.f);
    o.z = fmaxf(M + c.z + bv - a.z, 0.f);
    o.w = fmaxf(M + c.w + bv - a.w, 0.f);
    *(float4*)(out + (size_t)(b * PD + r0 + r) * PN + (t << 2)) = o;
  }
}

extern "C" void kernel_launch(void* const* d_in, const int* in_sizes, int n_in,
                              void* d_out, int out_size, void* d_ws, size_t ws_size,
                              hipStream_t stream) {
  const float* x = (const float*)d_in[0];
  const float* W1 = (const float*)d_in[1];
  const float* W2 = (const float*)d_in[2];
  const float* bias = (const float*)d_in[3];
  float* out = (float*)d_out;

  gcn_one<<<dim3(PB * PD / 2), dim3(512), 0, stream>>>(x, W1, W2, bias, out);
}